// Round 16
// baseline (624.696 us; speedup 1.0000x reference)
//
#include <hip/hip_runtime.h>
#include <hip/hip_bf16.h>

namespace {

constexpr int N    = 100000;
constexpr int M    = 12;
constexpr int ORIG = 92;
constexpr int NBR  = 41;
constexpr int F    = 64;
constexpr int H    = 128;
constexpr int N0   = 2000;
constexpr float EPS = 1e-5f;

constexpr int NBLK2 = N / 32;   // 3125 blocks of 32 atoms

typedef __attribute__((ext_vector_type(8))) short bf16x8;
typedef __attribute__((ext_vector_type(4))) float f32x4;
typedef float f32x4u __attribute__((ext_vector_type(4), aligned(4)));
typedef unsigned long long u64;

__device__ __forceinline__ float u2f(unsigned u){ float f; __builtin_memcpy(&f, &u, 4); return f; }

__device__ __forceinline__ float softplusf(float x){
  float t = __expf(-fabsf(x));
  return fmaxf(x, 0.f) + 0.693147180559945f * __log2f(1.f + t);
}
__device__ __forceinline__ float sigmoidf(float x){
  return __fdividef(1.f, 1.f + __expf(-x));
}
__device__ __forceinline__ unsigned short f2bf(float f){
  __hip_bfloat16 h = __float2bfloat16(f);
  unsigned short u; __builtin_memcpy(&u, &h, 2); return u;
}
__device__ __forceinline__ unsigned packbf2(float lo, float hi){
  __hip_bfloat162 b2 = __float22bfloat162_rn(make_float2(lo, hi));
  unsigned u; __builtin_memcpy(&u, &b2, 4); return u;
}
__device__ __forceinline__ void cvt2(bf16x8& d, int e, float a, float b){
  unsigned u = packbf2(a, b);
  d[e]   = (short)(u & 0xffffu);
  d[e+1] = (short)(u >> 16);
}

// ---------------- embedding: a = atom_fea @ W_emb + b_emb ----------------
__global__ void k_embed(const float* __restrict__ af, const float* __restrict__ W,
                        const float* __restrict__ b, float* __restrict__ a){
  __shared__ float row[4][ORIG];
  int base = blockIdx.x * 4;
  for(int t = threadIdx.x; t < 4*ORIG; t += 256){
    row[t/ORIG][t%ORIG] = af[(size_t)(base + t/ORIG)*ORIG + (t%ORIG)];
  }
  __syncthreads();
  int i = base + (threadIdx.x >> 6);
  int j = threadIdx.x & 63;
  const float* r = row[threadIdx.x >> 6];
  float acc = b[j];
  #pragma unroll
  for(int k = 0; k < ORIG; k++) acc = fmaf(r[k], W[k*F + j], acc);
  a[(size_t)i*F + j] = acc;
}

// -------- W -> bf16 MFMA B-fragments (E-panel and S/P-panel) --------------
__global__ void k_prep(const float* __restrict__ W,
                       unsigned short* __restrict__ webf,
                       unsigned short* __restrict__ wspf){
  int b = blockIdx.x;
  int l = threadIdx.x, lr = l & 15, lg = l >> 4;
  if(b < 16){
    int ct = b >> 1, s = b & 1;
    unsigned short* dst = webf + ((size_t)b*64 + l)*8;
    #pragma unroll
    for(int e = 0; e < 8; ++e){
      int k = s*32 + lg*8 + e;
      float w = (k < NBR) ? W[(size_t)(128 + k)*128 + ct*16 + lr] : 0.f;
      dst[e] = f2bf(w);
    }
  } else {
    int f = b - 16;
    int ct = f >> 1, ks = f & 1;
    int col = ct*16 + lr;
    unsigned short* dst = wspf + ((size_t)f*64 + l)*8;
    #pragma unroll
    for(int e = 0; e < 8; ++e){
      int k = ks*32 + lg*8 + e;
      float w = (col < 128) ? W[(size_t)k*128 + col]
                            : W[(size_t)(64 + k)*128 + (col - 128)];
      dst[e] = f2bf(w);
    }
  }
}

// ---------------- S/P GEMM via MFMA: (N x 64) @ (64 x 256) ----------------
// EPI=0: X is the input activation (f32), read directly.
// EPI=1: input a1 = softplus(A0 + bn2(SUMb)) computed in-register (layer-0
//        epilogue fused); w==0 wave also writes a1 to XO for the final
//        pool/head kernel. Removes the standalone k_epi round-trip.
template<int EPI>
__global__ __launch_bounds__(256, 3)
void k_spmm(const float* __restrict__ X, const unsigned short* __restrict__ wspf,
            const float* __restrict__ bias,
            unsigned* __restrict__ SU, u64* __restrict__ Q,
            const float* __restrict__ SUMb, const float* __restrict__ sc2,
            const float* __restrict__ sh2, float* __restrict__ XO){
  const int tid = threadIdx.x;
  const int l = tid & 63, lr = l & 15, lg = l >> 4;
  const int w = tid >> 6;
  const int a0 = blockIdx.x * 32;
  const bf16x8* wv = (const bf16x8*)wspf;

  float scv[2][8], shv[2][8];
  if(EPI){
    #pragma unroll
    for(int ks = 0; ks < 2; ++ks)
      #pragma unroll
      for(int u = 0; u < 8; ++u){
        scv[ks][u] = sc2[ks*32 + lg*8 + u];
        shv[ks][u] = sh2[ks*32 + lg*8 + u];
      }
  }

  bf16x8 A[2][2];
  #pragma unroll
  for(int t = 0; t < 2; ++t){
    size_t row = (size_t)(a0 + t*16 + lr);
    #pragma unroll
    for(int ks = 0; ks < 2; ++ks){
      const float* xr = X + row*64 + ks*32 + lg*8;
      f32x4u v0 = *(const f32x4u*)(xr);
      f32x4u v1 = *(const f32x4u*)(xr + 4);
      if(EPI){
        const float* sr = SUMb + row*64 + ks*32 + lg*8;
        f32x4u s0 = *(const f32x4u*)(sr);
        f32x4u s1 = *(const f32x4u*)(sr + 4);
        float y[8];
        #pragma unroll
        for(int u = 0; u < 4; ++u){
          y[u]     = softplusf(v0[u] + fmaf(s0[u], scv[ks][u],     shv[ks][u]));
          y[4 + u] = softplusf(v1[u] + fmaf(s1[u], scv[ks][4 + u], shv[ks][4 + u]));
        }
        cvt2(A[t][ks], 0, y[0], y[1]); cvt2(A[t][ks], 2, y[2], y[3]);
        cvt2(A[t][ks], 4, y[4], y[5]); cvt2(A[t][ks], 6, y[6], y[7]);
        if(w == 0){
          f32x4 o0 = {y[0], y[1], y[2], y[3]};
          f32x4 o1 = {y[4], y[5], y[6], y[7]};
          *(f32x4*)(XO + row*64 + ks*32 + lg*8)     = o0;
          *(f32x4*)(XO + row*64 + ks*32 + lg*8 + 4) = o1;
        }
      } else {
        cvt2(A[t][ks], 0, v0.x, v0.y); cvt2(A[t][ks], 2, v0.z, v0.w);
        cvt2(A[t][ks], 4, v1.x, v1.y); cvt2(A[t][ks], 6, v1.z, v1.w);
      }
    }
  }

  const bool isS = (w < 2);
  const int hh = isS ? w : (w - 2);
  int tl[4];
  if(isS){ tl[0] = 2*w; tl[1] = 2*w + 1; tl[2] = 4 + 2*w; tl[3] = 5 + 2*w; }
  else   { tl[0] = 8 + 2*hh; tl[1] = 9 + 2*hh; tl[2] = 12 + 2*hh; tl[3] = 13 + 2*hh; }

  bf16x8 B[4][2];
  #pragma unroll
  for(int ct = 0; ct < 4; ++ct)
    #pragma unroll
    for(int ks = 0; ks < 2; ++ks)
      B[ct][ks] = wv[((size_t)tl[ct]*2 + ks)*64 + l];

  f32x4 D[2][4];
  #pragma unroll
  for(int t = 0; t < 2; ++t)
    #pragma unroll
    for(int ct = 0; ct < 4; ++ct){
      f32x4 z = {0.f,0.f,0.f,0.f};
      z = __builtin_amdgcn_mfma_f32_16x16x32_bf16(A[t][0], B[ct][0], z, 0, 0, 0);
      z = __builtin_amdgcn_mfma_f32_16x16x32_bf16(A[t][1], B[ct][1], z, 0, 0, 0);
      D[t][ct] = z;
    }

  if(isS){
    float blo[2], bhi[2];
    #pragma unroll
    for(int ct = 0; ct < 2; ++ct){
      blo[ct] = bias[32*w + ct*16 + lr];
      bhi[ct] = bias[64 + 32*w + ct*16 + lr];
    }
    #pragma unroll
    for(int t = 0; t < 2; ++t)
      #pragma unroll
      for(int r = 0; r < 4; ++r){
        size_t row = a0 + t*16 + lg*4 + r;
        #pragma unroll
        for(int ct = 0; ct < 2; ++ct)
          SU[row*64 + 32*w + ct*16 + lr] =
            packbf2(D[t][ct][r] + blo[ct], D[t][2 + ct][r] + bhi[ct]);
      }
  } else {
    #pragma unroll
    for(int t = 0; t < 2; ++t)
      #pragma unroll
      for(int r = 0; r < 4; ++r){
        size_t row = a0 + t*16 + lg*4 + r;
        unsigned p0 = packbf2(D[t][0][r], D[t][2][r]);
        unsigned p1 = packbf2(D[t][1][r], D[t][3][r]);
        Q[row*32 + hh*16 + lr] = ((u64)p1 << 32) | p0;
      }
  }
}

// ------- layer-0 stats pass + nbr f32->bf16 conversion (writes NB) --------
// NB stores balanced across col-half waves: h==(m&1) stores iteration m
// (both halves compute identical A-fragments for their tile).
__global__ __launch_bounds__(256, 3)
void k_statcvt(const unsigned* __restrict__ SU, const u64* __restrict__ Q,
               const float* __restrict__ nbr, unsigned short* __restrict__ NB,
               const int* __restrict__ idx, const unsigned short* __restrict__ webf,
               float* __restrict__ part){
  const int tid = threadIdx.x;
  const int l = tid & 63, lr = l & 15, lg = l >> 4;
  const int wid = tid >> 6, tw = wid >> 1, h = wid & 1;
  const int a0 = blockIdx.x*32 + tw*16;

  bf16x8 Bf[4][2];
  const bf16x8* wv = (const bf16x8*)webf;
  #pragma unroll
  for(int c = 0; c < 4; ++c){
    int cg = (c < 2) ? (2*h + c) : (4 + 2*h + (c - 2));
    Bf[c][0] = wv[(cg*2 + 0)*64 + l];
    Bf[c][1] = wv[(cg*2 + 1)*64 + l];
  }

  unsigned SDu[2][4];
  #pragma unroll
  for(int fc = 0; fc < 2; ++fc)
    #pragma unroll
    for(int r = 0; r < 4; ++r)
      SDu[fc][r] = SU[(size_t)(a0 + lg*4 + r)*64 + h*32 + fc*16 + lr];

  __shared__ int six[32*M];
  for(int u = tid; u < 32*M; u += 256) six[u] = idx[(size_t)blockIdx.x*32*M + u];
  __syncthreads();

  float sg[4] = {0,0,0,0}, ssg[4] = {0,0,0,0};

  const float* fbase = nbr + (size_t)(a0 + lr)*M*NBR;
  unsigned short* nbt = NB + (size_t)(blockIdx.x*2 + tw)*M*768 + lr*48;

  #pragma unroll 1
  for(int m = 0; m < M; ++m){
    const float* nrow = fbase + (size_t)m*NBR;
    bf16x8 A0v, A1v = {0,0,0,0,0,0,0,0};
    {
      f32x4u v0 = *(const f32x4u*)(nrow + lg*8);
      f32x4u v1 = *(const f32x4u*)(nrow + lg*8 + 4);
      cvt2(A0v, 0, v0.x, v0.y); cvt2(A0v, 2, v0.z, v0.w);
      cvt2(A0v, 4, v1.x, v1.y); cvt2(A0v, 6, v1.z, v1.w);
    }
    if(lg == 0){
      f32x4u w0 = *(const f32x4u*)(nrow + 32);
      f32x4u w1 = *(const f32x4u*)(nrow + 36);
      cvt2(A1v, 0, w0.x, w0.y); cvt2(A1v, 2, w0.z, w0.w);
      cvt2(A1v, 4, w1.x, w1.y); cvt2(A1v, 6, w1.z, w1.w);
    } else if(lg == 1){
      A1v[0] = (short)f2bf(nrow[40]);
    }
    if(h == (m & 1)){
      *(bf16x8*)(nbt + (size_t)m*768 + lg*8) = A0v;
      if(lg < 2) *(bf16x8*)(nbt + (size_t)m*768 + 32 + lg*8) = A1v;
    }

    f32x4 D[4];
    #pragma unroll
    for(int c = 0; c < 4; ++c){
      f32x4 z = {0.f,0.f,0.f,0.f};
      z = __builtin_amdgcn_mfma_f32_16x16x32_bf16(A0v, Bf[c][0], z, 0, 0, 0);
      z = __builtin_amdgcn_mfma_f32_16x16x32_bf16(A1v, Bf[c][1], z, 0, 0, 0);
      D[c] = z;
    }

    #pragma unroll
    for(int r = 0; r < 4; ++r){
      int p = six[(tw*16 + lg*4 + r)*M + m];
      u64 q = Q[(size_t)p*32 + h*16 + lr];
      unsigned pvs[2];
      pvs[0] = (unsigned)(q & 0xffffffffull);
      pvs[1] = (unsigned)(q >> 32);
      #pragma unroll
      for(int fc = 0; fc < 2; ++fc){
        unsigned pv = pvs[fc];
        unsigned sv = SDu[fc][r];
        float gf = D[fc][r]     + u2f(sv << 16)         + u2f(pv << 16);
        float gc = D[2 + fc][r] + u2f(sv & 0xffff0000u) + u2f(pv & 0xffff0000u);
        sg[fc]     += gf;  ssg[fc]     = fmaf(gf, gf, ssg[fc]);
        sg[2 + fc] += gc;  ssg[2 + fc] = fmaf(gc, gc, ssg[2 + fc]);
      }
    }
  }

  #pragma unroll
  for(int c = 0; c < 4; ++c){
    sg[c]  += __shfl_xor(sg[c], 16, 64);  sg[c]  += __shfl_xor(sg[c], 32, 64);
    ssg[c] += __shfl_xor(ssg[c], 16, 64); ssg[c] += __shfl_xor(ssg[c], 32, 64);
  }
  if(lg == 0){
    float* pb = part + ((size_t)blockIdx.x*2 + tw)*256;
    #pragma unroll
    for(int c = 0; c < 4; ++c){
      int col = (c < 2) ? (h*32 + c*16 + lr) : (64 + h*32 + (c - 2)*16 + lr);
      pb[col]       = sg[c];
      pb[128 + col] = ssg[c];
    }
  }
}

// ---------------- unified MFMA pass over (atom, m) rows -------------------
template<int MODE, int NBF>
__global__ __launch_bounds__(256, 4)
void k_pass2(const unsigned* __restrict__ SU, const u64* __restrict__ Q,
             const float* __restrict__ nbr, const unsigned short* __restrict__ NB,
             const int* __restrict__ idx, const unsigned short* __restrict__ webf,
             const float* __restrict__ sc1, const float* __restrict__ sh1,
             float* __restrict__ SUMb, float* __restrict__ part){
  const int tid = threadIdx.x;
  const int l = tid & 63, lr = l & 15, lg = l >> 4;
  const int wid = tid >> 6, tw = wid >> 1, h = wid & 1;
  const int a0 = blockIdx.x*32 + tw*16;

  bf16x8 Bf[4][2];
  const bf16x8* wv = (const bf16x8*)webf;
  #pragma unroll
  for(int c = 0; c < 4; ++c){
    int cg = (c < 2) ? (2*h + c) : (4 + 2*h + (c - 2));
    Bf[c][0] = wv[(cg*2 + 0)*64 + l];
    Bf[c][1] = wv[(cg*2 + 1)*64 + l];
  }

  unsigned SDu[2][4];
  #pragma unroll
  for(int fc = 0; fc < 2; ++fc)
    #pragma unroll
    for(int r = 0; r < 4; ++r)
      SDu[fc][r] = SU[(size_t)(a0 + lg*4 + r)*64 + h*32 + fc*16 + lr];

  __shared__ int six[32*M];
  for(int u = tid; u < 32*M; u += 256) six[u] = idx[(size_t)blockIdx.x*32*M + u];
  __syncthreads();

  float c1f[2], h1f[2], c1c[2], h1c[2];
  if(MODE == 1){
    #pragma unroll
    for(int fc = 0; fc < 2; ++fc){
      int j = h*32 + fc*16 + lr;
      c1f[fc] = sc1[j];      h1f[fc] = sh1[j];
      c1c[fc] = sc1[64 + j]; h1c[fc] = sh1[64 + j];
    }
  }

  float sg[4] = {0,0,0,0}, ssg[4] = {0,0,0,0};
  float sact[4][2];
  #pragma unroll
  for(int r = 0; r < 4; ++r){ sact[r][0] = 0.f; sact[r][1] = 0.f; }

  const unsigned short* nb_tile;
  const float* fbase;
  if constexpr(NBF) nb_tile = NB + (size_t)(blockIdx.x*2 + tw)*M*768;
  else              fbase = nbr + (size_t)(a0 + lr)*M*NBR;

  #define LOAD_A(mm, A0o, A1o)                                              \
    do{                                                                     \
      if constexpr(NBF){                                                    \
        const unsigned short* nrow = nb_tile + (size_t)(mm)*768 + lr*48;    \
        A0o = *(const bf16x8*)(nrow + lg*8);                                \
        if(lg < 2) A1o = *(const bf16x8*)(nrow + 32 + lg*8);                \
        else       A1o = (bf16x8){0,0,0,0,0,0,0,0};                         \
      } else {                                                              \
        const float* nrow = fbase + (size_t)(mm)*NBR;                       \
        f32x4u v0 = *(const f32x4u*)(nrow + lg*8);                          \
        f32x4u v1 = *(const f32x4u*)(nrow + lg*8 + 4);                      \
        cvt2(A0o, 0, v0.x, v0.y); cvt2(A0o, 2, v0.z, v0.w);                 \
        cvt2(A0o, 4, v1.x, v1.y); cvt2(A0o, 6, v1.z, v1.w);                 \
        A1o = (bf16x8){0,0,0,0,0,0,0,0};                                    \
        if(lg == 0){                                                        \
          f32x4u w0 = *(const f32x4u*)(nrow + 32);                          \
          f32x4u w1 = *(const f32x4u*)(nrow + 36);                          \
          cvt2(A1o, 0, w0.x, w0.y); cvt2(A1o, 2, w0.z, w0.w);               \
          cvt2(A1o, 4, w1.x, w1.y); cvt2(A1o, 6, w1.z, w1.w);               \
        } else if(lg == 1){                                                 \
          A1o[0] = (short)f2bf(nrow[40]);                                   \
        }                                                                   \
      }                                                                     \
    }while(0)

  bf16x8 cA0, cA1, nA0, nA1;
  LOAD_A(0, cA0, cA1);

  #pragma unroll 1
  for(int m = 0; m < M; ++m){
    if(m + 1 < M) LOAD_A(m + 1, nA0, nA1);

    f32x4 D[4];
    #pragma unroll
    for(int c = 0; c < 4; ++c){
      f32x4 z = {0.f,0.f,0.f,0.f};
      z = __builtin_amdgcn_mfma_f32_16x16x32_bf16(cA0, Bf[c][0], z, 0, 0, 0);
      z = __builtin_amdgcn_mfma_f32_16x16x32_bf16(cA1, Bf[c][1], z, 0, 0, 0);
      D[c] = z;
    }

    #pragma unroll
    for(int r = 0; r < 4; ++r){
      int p = six[(tw*16 + lg*4 + r)*M + m];
      u64 q = Q[(size_t)p*32 + h*16 + lr];
      unsigned pvs[2];
      pvs[0] = (unsigned)(q & 0xffffffffull);
      pvs[1] = (unsigned)(q >> 32);
      #pragma unroll
      for(int fc = 0; fc < 2; ++fc){
        unsigned pv = pvs[fc];
        unsigned sv = SDu[fc][r];
        float gf = D[fc][r]     + u2f(sv << 16)         + u2f(pv << 16);
        float gc = D[2 + fc][r] + u2f(sv & 0xffff0000u) + u2f(pv & 0xffff0000u);
        if(MODE == 0){
          sg[fc]     += gf;  ssg[fc]     = fmaf(gf, gf, ssg[fc]);
          sg[2 + fc] += gc;  ssg[2 + fc] = fmaf(gc, gc, ssg[2 + fc]);
        } else {
          float bf_ = fmaf(gf, c1f[fc], h1f[fc]);
          float bc_ = fmaf(gc, c1c[fc], h1c[fc]);
          sact[r][fc] += sigmoidf(bf_) * softplusf(bc_);
        }
      }
    }
    cA0 = nA0; cA1 = nA1;
  }
  #undef LOAD_A

  if(MODE == 0){
    #pragma unroll
    for(int c = 0; c < 4; ++c){
      sg[c]  += __shfl_xor(sg[c], 16, 64);  sg[c]  += __shfl_xor(sg[c], 32, 64);
      ssg[c] += __shfl_xor(ssg[c], 16, 64); ssg[c] += __shfl_xor(ssg[c], 32, 64);
    }
    if(lg == 0){
      float* pb = part + ((size_t)blockIdx.x*2 + tw)*256;
      #pragma unroll
      for(int c = 0; c < 4; ++c){
        int col = (c < 2) ? (h*32 + c*16 + lr) : (64 + h*32 + (c - 2)*16 + lr);
        pb[col]       = sg[c];
        pb[128 + col] = ssg[c];
      }
    }
  } else {
    float ps[2] = {0,0}, pss[2] = {0,0};
    #pragma unroll
    for(int fc = 0; fc < 2; ++fc){
      #pragma unroll
      for(int r = 0; r < 4; ++r){
        float v = sact[r][fc];
        SUMb[(size_t)(a0 + lg*4 + r)*64 + h*32 + fc*16 + lr] = v;
        ps[fc] += v; pss[fc] = fmaf(v, v, pss[fc]);
      }
      ps[fc]  += __shfl_xor(ps[fc], 16, 64);  ps[fc]  += __shfl_xor(ps[fc], 32, 64);
      pss[fc] += __shfl_xor(pss[fc], 16, 64); pss[fc] += __shfl_xor(pss[fc], 32, 64);
    }
    if(lg == 0){
      float* pb = part + ((size_t)blockIdx.x*2 + tw)*128;
      #pragma unroll
      for(int fc = 0; fc < 2; ++fc){
        int j = h*32 + fc*16 + lr;
        pb[j]      = ps[fc];
        pb[64 + j] = pss[fc];
      }
    }
  }
}

// ------- fused column reduction + BN finalize: one block per channel ------
__global__ void k_redfin(const float* __restrict__ part, int nblocks, int width,
                         int nch, const float* __restrict__ gamma,
                         const float* __restrict__ beta,
                         float* __restrict__ sc, float* __restrict__ sh,
                         float inv){
  int j = blockIdx.x;
  float s = 0.f, ss = 0.f;
  for(int b = threadIdx.x; b < nblocks; b += 256){
    s  += part[(size_t)b*width + j];
    ss += part[(size_t)b*width + nch + j];
  }
  __shared__ float rs[256], rss[256];
  rs[threadIdx.x] = s; rss[threadIdx.x] = ss;
  __syncthreads();
  for(int off = 128; off; off >>= 1){
    if(threadIdx.x < off){
      rs[threadIdx.x]  += rs[threadIdx.x + off];
      rss[threadIdx.x] += rss[threadIdx.x + off];
    }
    __syncthreads();
  }
  if(threadIdx.x == 0){
    float mu  = rs[0] * inv;
    float var = fmaxf(rss[0] * inv - mu*mu, 0.f);
    float r   = rsqrtf(var + EPS);
    float g   = gamma[j] * r;
    sc[j] = g;
    sh[j] = beta[j] - mu * g;
  }
}

// ---- fused layer-1 epilogue + segment-mean pool + head, per crystal ------
__global__ void k_poolhead(const float* __restrict__ X, const float* __restrict__ SUMb,
                           const float* __restrict__ sc2, const float* __restrict__ sh2,
                           const int* __restrict__ cid,
                           const float* __restrict__ Wfc, const float* __restrict__ bfc,
                           const float* __restrict__ Wout, const float* __restrict__ bout,
                           float* __restrict__ out){
  int c = blockIdx.x;
  int t = threadIdx.x;
  int j = t & 63, half = t >> 6;

  int lo = 0, hi = N;
  while(lo < hi){ int mid = (lo + hi) >> 1; if(cid[mid] < c) lo = mid + 1; else hi = mid; }
  int s0 = lo;
  lo = s0; hi = N;
  while(lo < hi){ int mid = (lo + hi) >> 1; if(cid[mid] < c + 1) lo = mid + 1; else hi = mid; }
  int s1 = lo;

  float sc_j = sc2[j], sh_j = sh2[j];
  float acc = 0.f;
  for(int i = s0 + half; i < s1; i += 2){
    float x = X[(size_t)i*F + j];
    float s = SUMb[(size_t)i*F + j];
    float tv = softplusf(x + fmaf(s, sc_j, sh_j));
    acc += softplusf(tv + x);
  }
  __shared__ float ps[2][64];
  ps[half][j] = acc;
  __syncthreads();
  __shared__ float spv[F];
  if(t < 64)
    spv[t] = softplusf((ps[0][t] + ps[1][t]) / fmaxf((float)(s1 - s0), 1.f));
  __syncthreads();

  float hsum = bfc[t];
  #pragma unroll
  for(int k = 0; k < F; k++) hsum = fmaf(spv[k], Wfc[k*H + t], hsum);
  hsum = softplusf(hsum);
  float v = hsum * Wout[t];
  #pragma unroll
  for(int off = 32; off; off >>= 1) v += __shfl_down(v, off, 64);
  __shared__ float red[2];
  if((t & 63) == 0) red[t >> 6] = v;
  __syncthreads();
  if(t == 0) out[c] = red[0] + red[1] + bout[0];
}

// workspace offsets (bytes, all 16B-aligned)
constexpr size_t OFF_A0   = 0;
constexpr size_t OFF_A1   = 25600000;
constexpr size_t OFF_SUMB = 51200000;
constexpr size_t OFF_SU   = 76800000;
constexpr size_t OFF_Q    = 102400000;
constexpr size_t OFF_SP1  = 128512000;
constexpr size_t OFF_SP2  = 134912000;
constexpr size_t OFF_STAT = 138112000;
constexpr size_t OFF_WEBF = 138120192;
constexpr size_t OFF_WSPF = 138136576;
constexpr size_t OFF_NB   = 138169344;
constexpr size_t WS_NEED_NB = OFF_NB + (size_t)N*M*48*2;  // 253,369,344

} // namespace

extern "C" void kernel_launch(void* const* d_in, const int* in_sizes, int n_in,
                              void* d_out, int out_size, void* d_ws, size_t ws_size,
                              hipStream_t stream){
  const float* atom_fea = (const float*)d_in[0];
  const float* nbr_fea  = (const float*)d_in[1];
  const int*   nbr_idx  = (const int*)d_in[2];
  const int*   cid      = (const int*)d_in[3];
  const float* W_emb = (const float*)d_in[4];
  const float* b_emb = (const float*)d_in[5];
  const float* cW  = (const float*)d_in[6];
  const float* cb  = (const float*)d_in[7];
  const float* cg1 = (const float*)d_in[8];
  const float* cbt1= (const float*)d_in[9];
  const float* cg2 = (const float*)d_in[10];
  const float* cbt2= (const float*)d_in[11];
  const float* rW  = (const float*)d_in[12];
  const float* rb  = (const float*)d_in[13];
  const float* rg1 = (const float*)d_in[14];
  const float* rbt1= (const float*)d_in[15];
  const float* rg2 = (const float*)d_in[16];
  const float* rbt2= (const float*)d_in[17];
  const float* W_fc = (const float*)d_in[18];
  const float* b_fc = (const float*)d_in[19];
  const float* W_out= (const float*)d_in[20];
  const float* b_out= (const float*)d_in[21];
  float* out = (float*)d_out;

  char* ws = (char*)d_ws;
  float*    A0   = (float*)(ws + OFF_A0);
  float*    A1   = (float*)(ws + OFF_A1);
  float*    SUMb = (float*)(ws + OFF_SUMB);
  unsigned* SU   = (unsigned*)(ws + OFF_SU);
  u64*      Q    = (u64*)(ws + OFF_Q);
  float*    SP1  = (float*)(ws + OFF_SP1);
  float*    SP2  = (float*)(ws + OFF_SP2);
  float*    STAT = (float*)(ws + OFF_STAT);
  unsigned short* WEBf = (unsigned short*)(ws + OFF_WEBF);
  unsigned short* WSPf = (unsigned short*)(ws + OFF_WSPF);
  unsigned short* NB   = (unsigned short*)(ws + OFF_NB);
  float* SC1  = STAT + 384;
  float* SH1  = STAT + 512;
  float* SC2  = STAT + 640;
  float* SH2  = STAT + 704;

  const bool use_nb = (ws_size >= WS_NEED_NB);

  k_embed<<<N/4, 256, 0, stream>>>(atom_fea, W_emb, b_emb, A0);

  for(int layer = 0; layer < 2; layer++){
    const float* W   = layer ? rW   : cW;
    const float* bb  = layer ? rb   : cb;
    const float* g1  = layer ? rg1  : cg1;
    const float* bt1 = layer ? rbt1 : cbt1;
    const float* g2  = layer ? rg2  : cg2;
    const float* bt2 = layer ? rbt2 : cbt2;

    k_prep<<<48, 64, 0, stream>>>(W, WEBf, WSPf);
    if(layer == 0){
      k_spmm<0><<<NBLK2, 256, 0, stream>>>(A0, WSPf, bb, SU, Q,
                                           nullptr, nullptr, nullptr, nullptr);
    } else {
      // fused layer-0 epilogue: a1 = softplus(A0 + bn2(SUMb)); writes A1
      k_spmm<1><<<NBLK2, 256, 0, stream>>>(A0, WSPf, bb, SU, Q,
                                           SUMb, SC2, SH2, A1);
    }

    // stats pass
    if(layer == 0 && use_nb){
      k_statcvt<<<NBLK2, 256, 0, stream>>>(SU, Q, nbr_fea, NB, nbr_idx, WEBf, SP1);
    } else if(use_nb){
      k_pass2<0,1><<<NBLK2, 256, 0, stream>>>(SU, Q, nbr_fea, NB, nbr_idx,
                                              WEBf, nullptr, nullptr, nullptr, SP1);
    } else {
      k_pass2<0,0><<<NBLK2, 256, 0, stream>>>(SU, Q, nbr_fea, nullptr, nbr_idx,
                                              WEBf, nullptr, nullptr, nullptr, SP1);
    }
    k_redfin<<<128, 256, 0, stream>>>(SP1, 2*NBLK2, 256, 128, g1, bt1, SC1, SH1,
                                      1.f/(float)(N*M));
    // apply pass
    if(use_nb){
      k_pass2<1,1><<<NBLK2, 256, 0, stream>>>(SU, Q, nbr_fea, NB, nbr_idx,
                                              WEBf, SC1, SH1, SUMb, SP2);
    } else {
      k_pass2<1,0><<<NBLK2, 256, 0, stream>>>(SU, Q, nbr_fea, nullptr, nbr_idx,
                                              WEBf, SC1, SH1, SUMb, SP2);
    }
    k_redfin<<<64, 256, 0, stream>>>(SP2, 2*NBLK2, 128, 64, g2, bt2, SC2, SH2,
                                     1.f/(float)N);
  }

  // fused layer-1 epilogue + pool + head
  k_poolhead<<<N0, 128, 0, stream>>>(A1, SUMb, SC2, SH2, cid,
                                     W_fc, b_fc, W_out, b_out, out);
}

// Round 17
// 613.677 us; speedup vs baseline: 1.0180x; 1.0180x over previous
//
#include <hip/hip_runtime.h>
#include <hip/hip_bf16.h>

namespace {

constexpr int N    = 100000;
constexpr int M    = 12;
constexpr int ORIG = 92;
constexpr int NBR  = 41;
constexpr int F    = 64;
constexpr int H    = 128;
constexpr int N0   = 2000;
constexpr float EPS = 1e-5f;

constexpr int NBLK2 = N / 32;   // 3125 blocks of 32 atoms

typedef __attribute__((ext_vector_type(8))) short bf16x8;
typedef __attribute__((ext_vector_type(4))) float f32x4;
typedef float f32x4u __attribute__((ext_vector_type(4), aligned(4)));
typedef unsigned long long u64;

__device__ __forceinline__ float u2f(unsigned u){ float f; __builtin_memcpy(&f, &u, 4); return f; }

__device__ __forceinline__ float softplusf(float x){
  float t = __expf(-fabsf(x));
  return fmaxf(x, 0.f) + 0.693147180559945f * __log2f(1.f + t);
}
__device__ __forceinline__ float sigmoidf(float x){
  return __fdividef(1.f, 1.f + __expf(-x));
}
__device__ __forceinline__ unsigned short f2bf(float f){
  __hip_bfloat16 h = __float2bfloat16(f);
  unsigned short u; __builtin_memcpy(&u, &h, 2); return u;
}
__device__ __forceinline__ unsigned packbf2(float lo, float hi){
  __hip_bfloat162 b2 = __float22bfloat162_rn(make_float2(lo, hi));
  unsigned u; __builtin_memcpy(&u, &b2, 4); return u;
}
__device__ __forceinline__ void cvt2(bf16x8& d, int e, float a, float b){
  unsigned u = packbf2(a, b);
  d[e]   = (short)(u & 0xffffu);
  d[e+1] = (short)(u >> 16);
}

// ---------------- embedding: a = atom_fea @ W_emb + b_emb ----------------
__global__ void k_embed(const float* __restrict__ af, const float* __restrict__ W,
                        const float* __restrict__ b, float* __restrict__ a){
  __shared__ float row[4][ORIG];
  int base = blockIdx.x * 4;
  for(int t = threadIdx.x; t < 4*ORIG; t += 256){
    row[t/ORIG][t%ORIG] = af[(size_t)(base + t/ORIG)*ORIG + (t%ORIG)];
  }
  __syncthreads();
  int i = base + (threadIdx.x >> 6);
  int j = threadIdx.x & 63;
  const float* r = row[threadIdx.x >> 6];
  float acc = b[j];
  #pragma unroll
  for(int k = 0; k < ORIG; k++) acc = fmaf(r[k], W[k*F + j], acc);
  a[(size_t)i*F + j] = acc;
}

// -------- W -> bf16 MFMA B-fragments (E-panel and S/P-panel) --------------
__global__ void k_prep(const float* __restrict__ W,
                       unsigned short* __restrict__ webf,
                       unsigned short* __restrict__ wspf){
  int b = blockIdx.x;
  int l = threadIdx.x, lr = l & 15, lg = l >> 4;
  if(b < 16){
    int ct = b >> 1, s = b & 1;
    unsigned short* dst = webf + ((size_t)b*64 + l)*8;
    #pragma unroll
    for(int e = 0; e < 8; ++e){
      int k = s*32 + lg*8 + e;
      float w = (k < NBR) ? W[(size_t)(128 + k)*128 + ct*16 + lr] : 0.f;
      dst[e] = f2bf(w);
    }
  } else {
    int f = b - 16;
    int ct = f >> 1, ks = f & 1;
    int col = ct*16 + lr;
    unsigned short* dst = wspf + ((size_t)f*64 + l)*8;
    #pragma unroll
    for(int e = 0; e < 8; ++e){
      int k = ks*32 + lg*8 + e;
      float w = (col < 128) ? W[(size_t)k*128 + col]
                            : W[(size_t)(64 + k)*128 + (col - 128)];
      dst[e] = f2bf(w);
    }
  }
}

// ---------------- S/P GEMM via MFMA: (N x 64) @ (64 x 256) ----------------
// Waves 0,1: S tiles -> SU packed (c, c+64) pairs.
// Waves 2,3 (hh=w-2): P tiles -> Q u64 per row-half.
__global__ __launch_bounds__(256, 3)
void k_spmm(const float* __restrict__ X, const unsigned short* __restrict__ wspf,
            const float* __restrict__ bias,
            unsigned* __restrict__ SU, u64* __restrict__ Q){
  const int tid = threadIdx.x;
  const int l = tid & 63, lr = l & 15, lg = l >> 4;
  const int w = tid >> 6;
  const int a0 = blockIdx.x * 32;
  const bf16x8* wv = (const bf16x8*)wspf;

  bf16x8 A[2][2];
  #pragma unroll
  for(int t = 0; t < 2; ++t){
    const float* xr = X + (size_t)(a0 + t*16 + lr)*64;
    #pragma unroll
    for(int ks = 0; ks < 2; ++ks){
      f32x4u v0 = *(const f32x4u*)(xr + ks*32 + lg*8);
      f32x4u v1 = *(const f32x4u*)(xr + ks*32 + lg*8 + 4);
      cvt2(A[t][ks], 0, v0.x, v0.y); cvt2(A[t][ks], 2, v0.z, v0.w);
      cvt2(A[t][ks], 4, v1.x, v1.y); cvt2(A[t][ks], 6, v1.z, v1.w);
    }
  }

  const bool isS = (w < 2);
  const int hh = isS ? w : (w - 2);
  int tl[4];
  if(isS){ tl[0] = 2*w; tl[1] = 2*w + 1; tl[2] = 4 + 2*w; tl[3] = 5 + 2*w; }
  else   { tl[0] = 8 + 2*hh; tl[1] = 9 + 2*hh; tl[2] = 12 + 2*hh; tl[3] = 13 + 2*hh; }

  bf16x8 B[4][2];
  #pragma unroll
  for(int ct = 0; ct < 4; ++ct)
    #pragma unroll
    for(int ks = 0; ks < 2; ++ks)
      B[ct][ks] = wv[((size_t)tl[ct]*2 + ks)*64 + l];

  f32x4 D[2][4];
  #pragma unroll
  for(int t = 0; t < 2; ++t)
    #pragma unroll
    for(int ct = 0; ct < 4; ++ct){
      f32x4 z = {0.f,0.f,0.f,0.f};
      z = __builtin_amdgcn_mfma_f32_16x16x32_bf16(A[t][0], B[ct][0], z, 0, 0, 0);
      z = __builtin_amdgcn_mfma_f32_16x16x32_bf16(A[t][1], B[ct][1], z, 0, 0, 0);
      D[t][ct] = z;
    }

  if(isS){
    float blo[2], bhi[2];
    #pragma unroll
    for(int ct = 0; ct < 2; ++ct){
      blo[ct] = bias[32*w + ct*16 + lr];
      bhi[ct] = bias[64 + 32*w + ct*16 + lr];
    }
    #pragma unroll
    for(int t = 0; t < 2; ++t)
      #pragma unroll
      for(int r = 0; r < 4; ++r){
        size_t row = a0 + t*16 + lg*4 + r;
        #pragma unroll
        for(int ct = 0; ct < 2; ++ct)
          SU[row*64 + 32*w + ct*16 + lr] =
            packbf2(D[t][ct][r] + blo[ct], D[t][2 + ct][r] + bhi[ct]);
      }
  } else {
    #pragma unroll
    for(int t = 0; t < 2; ++t)
      #pragma unroll
      for(int r = 0; r < 4; ++r){
        size_t row = a0 + t*16 + lg*4 + r;
        unsigned p0 = packbf2(D[t][0][r], D[t][2][r]);
        unsigned p1 = packbf2(D[t][1][r], D[t][3][r]);
        Q[row*32 + hh*16 + lr] = ((u64)p1 << 32) | p0;
      }
  }
}

// ------- layer-0 stats pass + nbr f32->bf16 conversion (writes NB) --------
// NB stores balanced across col-half waves: h==(m&1) stores iteration m
// (both halves compute identical A-fragments for their tile).
__global__ __launch_bounds__(256, 3)
void k_statcvt(const unsigned* __restrict__ SU, const u64* __restrict__ Q,
               const float* __restrict__ nbr, unsigned short* __restrict__ NB,
               const int* __restrict__ idx, const unsigned short* __restrict__ webf,
               float* __restrict__ part){
  const int tid = threadIdx.x;
  const int l = tid & 63, lr = l & 15, lg = l >> 4;
  const int wid = tid >> 6, tw = wid >> 1, h = wid & 1;
  const int a0 = blockIdx.x*32 + tw*16;

  bf16x8 Bf[4][2];
  const bf16x8* wv = (const bf16x8*)webf;
  #pragma unroll
  for(int c = 0; c < 4; ++c){
    int cg = (c < 2) ? (2*h + c) : (4 + 2*h + (c - 2));
    Bf[c][0] = wv[(cg*2 + 0)*64 + l];
    Bf[c][1] = wv[(cg*2 + 1)*64 + l];
  }

  unsigned SDu[2][4];
  #pragma unroll
  for(int fc = 0; fc < 2; ++fc)
    #pragma unroll
    for(int r = 0; r < 4; ++r)
      SDu[fc][r] = SU[(size_t)(a0 + lg*4 + r)*64 + h*32 + fc*16 + lr];

  __shared__ int six[32*M];
  for(int u = tid; u < 32*M; u += 256) six[u] = idx[(size_t)blockIdx.x*32*M + u];
  __syncthreads();

  float sg[4] = {0,0,0,0}, ssg[4] = {0,0,0,0};

  const float* fbase = nbr + (size_t)(a0 + lr)*M*NBR;
  unsigned short* nbt = NB + (size_t)(blockIdx.x*2 + tw)*M*768 + lr*48;

  #pragma unroll 1
  for(int m = 0; m < M; ++m){
    const float* nrow = fbase + (size_t)m*NBR;
    bf16x8 A0v, A1v = {0,0,0,0,0,0,0,0};
    {
      f32x4u v0 = *(const f32x4u*)(nrow + lg*8);
      f32x4u v1 = *(const f32x4u*)(nrow + lg*8 + 4);
      cvt2(A0v, 0, v0.x, v0.y); cvt2(A0v, 2, v0.z, v0.w);
      cvt2(A0v, 4, v1.x, v1.y); cvt2(A0v, 6, v1.z, v1.w);
    }
    if(lg == 0){
      f32x4u w0 = *(const f32x4u*)(nrow + 32);
      f32x4u w1 = *(const f32x4u*)(nrow + 36);
      cvt2(A1v, 0, w0.x, w0.y); cvt2(A1v, 2, w0.z, w0.w);
      cvt2(A1v, 4, w1.x, w1.y); cvt2(A1v, 6, w1.z, w1.w);
    } else if(lg == 1){
      A1v[0] = (short)f2bf(nrow[40]);
    }
    if(h == (m & 1)){
      *(bf16x8*)(nbt + (size_t)m*768 + lg*8) = A0v;
      if(lg < 2) *(bf16x8*)(nbt + (size_t)m*768 + 32 + lg*8) = A1v;
    }

    f32x4 D[4];
    #pragma unroll
    for(int c = 0; c < 4; ++c){
      f32x4 z = {0.f,0.f,0.f,0.f};
      z = __builtin_amdgcn_mfma_f32_16x16x32_bf16(A0v, Bf[c][0], z, 0, 0, 0);
      z = __builtin_amdgcn_mfma_f32_16x16x32_bf16(A1v, Bf[c][1], z, 0, 0, 0);
      D[c] = z;
    }

    #pragma unroll
    for(int r = 0; r < 4; ++r){
      int p = six[(tw*16 + lg*4 + r)*M + m];
      u64 q = Q[(size_t)p*32 + h*16 + lr];
      unsigned pvs[2];
      pvs[0] = (unsigned)(q & 0xffffffffull);
      pvs[1] = (unsigned)(q >> 32);
      #pragma unroll
      for(int fc = 0; fc < 2; ++fc){
        unsigned pv = pvs[fc];
        unsigned sv = SDu[fc][r];
        float gf = D[fc][r]     + u2f(sv << 16)         + u2f(pv << 16);
        float gc = D[2 + fc][r] + u2f(sv & 0xffff0000u) + u2f(pv & 0xffff0000u);
        sg[fc]     += gf;  ssg[fc]     = fmaf(gf, gf, ssg[fc]);
        sg[2 + fc] += gc;  ssg[2 + fc] = fmaf(gc, gc, ssg[2 + fc]);
      }
    }
  }

  #pragma unroll
  for(int c = 0; c < 4; ++c){
    sg[c]  += __shfl_xor(sg[c], 16, 64);  sg[c]  += __shfl_xor(sg[c], 32, 64);
    ssg[c] += __shfl_xor(ssg[c], 16, 64); ssg[c] += __shfl_xor(ssg[c], 32, 64);
  }
  if(lg == 0){
    float* pb = part + ((size_t)blockIdx.x*2 + tw)*256;
    #pragma unroll
    for(int c = 0; c < 4; ++c){
      int col = (c < 2) ? (h*32 + c*16 + lr) : (64 + h*32 + (c - 2)*16 + lr);
      pb[col]       = sg[c];
      pb[128 + col] = ssg[c];
    }
  }
}

// ---------------- unified MFMA pass over (atom, m) rows -------------------
template<int MODE, int NBF>
__global__ __launch_bounds__(256, 4)
void k_pass2(const unsigned* __restrict__ SU, const u64* __restrict__ Q,
             const float* __restrict__ nbr, const unsigned short* __restrict__ NB,
             const int* __restrict__ idx, const unsigned short* __restrict__ webf,
             const float* __restrict__ sc1, const float* __restrict__ sh1,
             float* __restrict__ SUMb, float* __restrict__ part){
  const int tid = threadIdx.x;
  const int l = tid & 63, lr = l & 15, lg = l >> 4;
  const int wid = tid >> 6, tw = wid >> 1, h = wid & 1;
  const int a0 = blockIdx.x*32 + tw*16;

  bf16x8 Bf[4][2];
  const bf16x8* wv = (const bf16x8*)webf;
  #pragma unroll
  for(int c = 0; c < 4; ++c){
    int cg = (c < 2) ? (2*h + c) : (4 + 2*h + (c - 2));
    Bf[c][0] = wv[(cg*2 + 0)*64 + l];
    Bf[c][1] = wv[(cg*2 + 1)*64 + l];
  }

  unsigned SDu[2][4];
  #pragma unroll
  for(int fc = 0; fc < 2; ++fc)
    #pragma unroll
    for(int r = 0; r < 4; ++r)
      SDu[fc][r] = SU[(size_t)(a0 + lg*4 + r)*64 + h*32 + fc*16 + lr];

  __shared__ int six[32*M];
  for(int u = tid; u < 32*M; u += 256) six[u] = idx[(size_t)blockIdx.x*32*M + u];
  __syncthreads();

  float c1f[2], h1f[2], c1c[2], h1c[2];
  if(MODE == 1){
    #pragma unroll
    for(int fc = 0; fc < 2; ++fc){
      int j = h*32 + fc*16 + lr;
      c1f[fc] = sc1[j];      h1f[fc] = sh1[j];
      c1c[fc] = sc1[64 + j]; h1c[fc] = sh1[64 + j];
    }
  }

  float sg[4] = {0,0,0,0}, ssg[4] = {0,0,0,0};
  float sact[4][2];
  #pragma unroll
  for(int r = 0; r < 4; ++r){ sact[r][0] = 0.f; sact[r][1] = 0.f; }

  const unsigned short* nb_tile;
  const float* fbase;
  if constexpr(NBF) nb_tile = NB + (size_t)(blockIdx.x*2 + tw)*M*768;
  else              fbase = nbr + (size_t)(a0 + lr)*M*NBR;

  #define LOAD_A(mm, A0o, A1o)                                              \
    do{                                                                     \
      if constexpr(NBF){                                                    \
        const unsigned short* nrow = nb_tile + (size_t)(mm)*768 + lr*48;    \
        A0o = *(const bf16x8*)(nrow + lg*8);                                \
        if(lg < 2) A1o = *(const bf16x8*)(nrow + 32 + lg*8);                \
        else       A1o = (bf16x8){0,0,0,0,0,0,0,0};                         \
      } else {                                                              \
        const float* nrow = fbase + (size_t)(mm)*NBR;                       \
        f32x4u v0 = *(const f32x4u*)(nrow + lg*8);                          \
        f32x4u v1 = *(const f32x4u*)(nrow + lg*8 + 4);                      \
        cvt2(A0o, 0, v0.x, v0.y); cvt2(A0o, 2, v0.z, v0.w);                 \
        cvt2(A0o, 4, v1.x, v1.y); cvt2(A0o, 6, v1.z, v1.w);                 \
        A1o = (bf16x8){0,0,0,0,0,0,0,0};                                    \
        if(lg == 0){                                                        \
          f32x4u w0 = *(const f32x4u*)(nrow + 32);                          \
          f32x4u w1 = *(const f32x4u*)(nrow + 36);                          \
          cvt2(A1o, 0, w0.x, w0.y); cvt2(A1o, 2, w0.z, w0.w);               \
          cvt2(A1o, 4, w1.x, w1.y); cvt2(A1o, 6, w1.z, w1.w);               \
        } else if(lg == 1){                                                 \
          A1o[0] = (short)f2bf(nrow[40]);                                   \
        }                                                                   \
      }                                                                     \
    }while(0)

  bf16x8 cA0, cA1, nA0, nA1;
  LOAD_A(0, cA0, cA1);

  #pragma unroll 1
  for(int m = 0; m < M; ++m){
    if(m + 1 < M) LOAD_A(m + 1, nA0, nA1);

    f32x4 D[4];
    #pragma unroll
    for(int c = 0; c < 4; ++c){
      f32x4 z = {0.f,0.f,0.f,0.f};
      z = __builtin_amdgcn_mfma_f32_16x16x32_bf16(cA0, Bf[c][0], z, 0, 0, 0);
      z = __builtin_amdgcn_mfma_f32_16x16x32_bf16(cA1, Bf[c][1], z, 0, 0, 0);
      D[c] = z;
    }

    #pragma unroll
    for(int r = 0; r < 4; ++r){
      int p = six[(tw*16 + lg*4 + r)*M + m];
      u64 q = Q[(size_t)p*32 + h*16 + lr];
      unsigned pvs[2];
      pvs[0] = (unsigned)(q & 0xffffffffull);
      pvs[1] = (unsigned)(q >> 32);
      #pragma unroll
      for(int fc = 0; fc < 2; ++fc){
        unsigned pv = pvs[fc];
        unsigned sv = SDu[fc][r];
        float gf = D[fc][r]     + u2f(sv << 16)         + u2f(pv << 16);
        float gc = D[2 + fc][r] + u2f(sv & 0xffff0000u) + u2f(pv & 0xffff0000u);
        if(MODE == 0){
          sg[fc]     += gf;  ssg[fc]     = fmaf(gf, gf, ssg[fc]);
          sg[2 + fc] += gc;  ssg[2 + fc] = fmaf(gc, gc, ssg[2 + fc]);
        } else {
          float bf_ = fmaf(gf, c1f[fc], h1f[fc]);
          float bc_ = fmaf(gc, c1c[fc], h1c[fc]);
          sact[r][fc] += sigmoidf(bf_) * softplusf(bc_);
        }
      }
    }
    cA0 = nA0; cA1 = nA1;
  }
  #undef LOAD_A

  if(MODE == 0){
    #pragma unroll
    for(int c = 0; c < 4; ++c){
      sg[c]  += __shfl_xor(sg[c], 16, 64);  sg[c]  += __shfl_xor(sg[c], 32, 64);
      ssg[c] += __shfl_xor(ssg[c], 16, 64); ssg[c] += __shfl_xor(ssg[c], 32, 64);
    }
    if(lg == 0){
      float* pb = part + ((size_t)blockIdx.x*2 + tw)*256;
      #pragma unroll
      for(int c = 0; c < 4; ++c){
        int col = (c < 2) ? (h*32 + c*16 + lr) : (64 + h*32 + (c - 2)*16 + lr);
        pb[col]       = sg[c];
        pb[128 + col] = ssg[c];
      }
    }
  } else {
    float ps[2] = {0,0}, pss[2] = {0,0};
    #pragma unroll
    for(int fc = 0; fc < 2; ++fc){
      #pragma unroll
      for(int r = 0; r < 4; ++r){
        float v = sact[r][fc];
        SUMb[(size_t)(a0 + lg*4 + r)*64 + h*32 + fc*16 + lr] = v;
        ps[fc] += v; pss[fc] = fmaf(v, v, pss[fc]);
      }
      ps[fc]  += __shfl_xor(ps[fc], 16, 64);  ps[fc]  += __shfl_xor(ps[fc], 32, 64);
      pss[fc] += __shfl_xor(pss[fc], 16, 64); pss[fc] += __shfl_xor(pss[fc], 32, 64);
    }
    if(lg == 0){
      float* pb = part + ((size_t)blockIdx.x*2 + tw)*128;
      #pragma unroll
      for(int fc = 0; fc < 2; ++fc){
        int j = h*32 + fc*16 + lr;
        pb[j]      = ps[fc];
        pb[64 + j] = pss[fc];
      }
    }
  }
}

// ------- fused column reduction + BN finalize: one block per channel ------
__global__ void k_redfin(const float* __restrict__ part, int nblocks, int width,
                         int nch, const float* __restrict__ gamma,
                         const float* __restrict__ beta,
                         float* __restrict__ sc, float* __restrict__ sh,
                         float inv){
  int j = blockIdx.x;
  float s = 0.f, ss = 0.f;
  for(int b = threadIdx.x; b < nblocks; b += 256){
    s  += part[(size_t)b*width + j];
    ss += part[(size_t)b*width + nch + j];
  }
  __shared__ float rs[256], rss[256];
  rs[threadIdx.x] = s; rss[threadIdx.x] = ss;
  __syncthreads();
  for(int off = 128; off; off >>= 1){
    if(threadIdx.x < off){
      rs[threadIdx.x]  += rs[threadIdx.x + off];
      rss[threadIdx.x] += rss[threadIdx.x + off];
    }
    __syncthreads();
  }
  if(threadIdx.x == 0){
    float mu  = rs[0] * inv;
    float var = fmaxf(rss[0] * inv - mu*mu, 0.f);
    float r   = rsqrtf(var + EPS);
    float g   = gamma[j] * r;
    sc[j] = g;
    sh[j] = beta[j] - mu * g;
  }
}

// ---------------- epilogue (layer 0): Y = softplus(X + BN2(summed)) -------
__global__ void k_epi(const float* __restrict__ X, const float* __restrict__ SUMb,
                      const float* __restrict__ sc2, const float* __restrict__ sh2,
                      float* __restrict__ Y){
  int stride = gridDim.x * blockDim.x;
  int total = N*F/4;
  for(int e4 = blockIdx.x * blockDim.x + threadIdx.x; e4 < total; e4 += stride){
    f32x4 x = *(const f32x4*)(X + (size_t)e4*4);
    f32x4 s = *(const f32x4*)(SUMb + (size_t)e4*4);
    int j0 = (e4*4) & 63;
    f32x4 y;
    #pragma unroll
    for(int u = 0; u < 4; ++u)
      y[u] = softplusf(x[u] + fmaf(s[u], sc2[j0 + u], sh2[j0 + u]));
    *(f32x4*)(Y + (size_t)e4*4) = y;
  }
}

// ---- fused layer-1 epilogue + segment-mean pool + head, per crystal ------
__global__ void k_poolhead(const float* __restrict__ X, const float* __restrict__ SUMb,
                           const float* __restrict__ sc2, const float* __restrict__ sh2,
                           const int* __restrict__ cid,
                           const float* __restrict__ Wfc, const float* __restrict__ bfc,
                           const float* __restrict__ Wout, const float* __restrict__ bout,
                           float* __restrict__ out){
  int c = blockIdx.x;
  int t = threadIdx.x;
  int j = t & 63, half = t >> 6;

  int lo = 0, hi = N;
  while(lo < hi){ int mid = (lo + hi) >> 1; if(cid[mid] < c) lo = mid + 1; else hi = mid; }
  int s0 = lo;
  lo = s0; hi = N;
  while(lo < hi){ int mid = (lo + hi) >> 1; if(cid[mid] < c + 1) lo = mid + 1; else hi = mid; }
  int s1 = lo;

  float sc_j = sc2[j], sh_j = sh2[j];
  float acc = 0.f;
  for(int i = s0 + half; i < s1; i += 2){
    float x = X[(size_t)i*F + j];
    float s = SUMb[(size_t)i*F + j];
    float tv = softplusf(x + fmaf(s, sc_j, sh_j));
    acc += softplusf(tv + x);
  }
  __shared__ float ps[2][64];
  ps[half][j] = acc;
  __syncthreads();
  __shared__ float spv[F];
  if(t < 64)
    spv[t] = softplusf((ps[0][t] + ps[1][t]) / fmaxf((float)(s1 - s0), 1.f));
  __syncthreads();

  float hsum = bfc[t];
  #pragma unroll
  for(int k = 0; k < F; k++) hsum = fmaf(spv[k], Wfc[k*H + t], hsum);
  hsum = softplusf(hsum);
  float v = hsum * Wout[t];
  #pragma unroll
  for(int off = 32; off; off >>= 1) v += __shfl_down(v, off, 64);
  __shared__ float red[2];
  if((t & 63) == 0) red[t >> 6] = v;
  __syncthreads();
  if(t == 0) out[c] = red[0] + red[1] + bout[0];
}

// workspace offsets (bytes, all 16B-aligned)
constexpr size_t OFF_A0   = 0;
constexpr size_t OFF_A1   = 25600000;
constexpr size_t OFF_SUMB = 51200000;
constexpr size_t OFF_SU   = 76800000;
constexpr size_t OFF_Q    = 102400000;
constexpr size_t OFF_SP1  = 128512000;
constexpr size_t OFF_SP2  = 134912000;
constexpr size_t OFF_STAT = 138112000;
constexpr size_t OFF_WEBF = 138120192;
constexpr size_t OFF_WSPF = 138136576;
constexpr size_t OFF_NB   = 138169344;
constexpr size_t WS_NEED_NB = OFF_NB + (size_t)N*M*48*2;  // 253,369,344

} // namespace

extern "C" void kernel_launch(void* const* d_in, const int* in_sizes, int n_in,
                              void* d_out, int out_size, void* d_ws, size_t ws_size,
                              hipStream_t stream){
  const float* atom_fea = (const float*)d_in[0];
  const float* nbr_fea  = (const float*)d_in[1];
  const int*   nbr_idx  = (const int*)d_in[2];
  const int*   cid      = (const int*)d_in[3];
  const float* W_emb = (const float*)d_in[4];
  const float* b_emb = (const float*)d_in[5];
  const float* cW  = (const float*)d_in[6];
  const float* cb  = (const float*)d_in[7];
  const float* cg1 = (const float*)d_in[8];
  const float* cbt1= (const float*)d_in[9];
  const float* cg2 = (const float*)d_in[10];
  const float* cbt2= (const float*)d_in[11];
  const float* rW  = (const float*)d_in[12];
  const float* rb  = (const float*)d_in[13];
  const float* rg1 = (const float*)d_in[14];
  const float* rbt1= (const float*)d_in[15];
  const float* rg2 = (const float*)d_in[16];
  const float* rbt2= (const float*)d_in[17];
  const float* W_fc = (const float*)d_in[18];
  const float* b_fc = (const float*)d_in[19];
  const float* W_out= (const float*)d_in[20];
  const float* b_out= (const float*)d_in[21];
  float* out = (float*)d_out;

  char* ws = (char*)d_ws;
  float*    A0   = (float*)(ws + OFF_A0);
  float*    A1   = (float*)(ws + OFF_A1);
  float*    SUMb = (float*)(ws + OFF_SUMB);
  unsigned* SU   = (unsigned*)(ws + OFF_SU);
  u64*      Q    = (u64*)(ws + OFF_Q);
  float*    SP1  = (float*)(ws + OFF_SP1);
  float*    SP2  = (float*)(ws + OFF_SP2);
  float*    STAT = (float*)(ws + OFF_STAT);
  unsigned short* WEBf = (unsigned short*)(ws + OFF_WEBF);
  unsigned short* WSPf = (unsigned short*)(ws + OFF_WSPF);
  unsigned short* NB   = (unsigned short*)(ws + OFF_NB);
  float* SC1  = STAT + 384;
  float* SH1  = STAT + 512;
  float* SC2  = STAT + 640;
  float* SH2  = STAT + 704;

  const bool use_nb = (ws_size >= WS_NEED_NB);

  k_embed<<<N/4, 256, 0, stream>>>(atom_fea, W_emb, b_emb, A0);

  for(int layer = 0; layer < 2; layer++){
    const float* W   = layer ? rW   : cW;
    const float* bb  = layer ? rb   : cb;
    const float* g1  = layer ? rg1  : cg1;
    const float* bt1 = layer ? rbt1 : cbt1;
    const float* g2  = layer ? rg2  : cg2;
    const float* bt2 = layer ? rbt2 : cbt2;
    const float* X = layer ? A1 : A0;

    k_prep<<<48, 64, 0, stream>>>(W, WEBf, WSPf);
    k_spmm<<<NBLK2, 256, 0, stream>>>(X, WSPf, bb, SU, Q);

    // stats pass
    if(layer == 0 && use_nb){
      k_statcvt<<<NBLK2, 256, 0, stream>>>(SU, Q, nbr_fea, NB, nbr_idx, WEBf, SP1);
    } else if(use_nb){
      k_pass2<0,1><<<NBLK2, 256, 0, stream>>>(SU, Q, nbr_fea, NB, nbr_idx,
                                              WEBf, nullptr, nullptr, nullptr, SP1);
    } else {
      k_pass2<0,0><<<NBLK2, 256, 0, stream>>>(SU, Q, nbr_fea, nullptr, nbr_idx,
                                              WEBf, nullptr, nullptr, nullptr, SP1);
    }
    k_redfin<<<128, 256, 0, stream>>>(SP1, 2*NBLK2, 256, 128, g1, bt1, SC1, SH1,
                                      1.f/(float)(N*M));
    // apply pass
    if(use_nb){
      k_pass2<1,1><<<NBLK2, 256, 0, stream>>>(SU, Q, nbr_fea, NB, nbr_idx,
                                              WEBf, SC1, SH1, SUMb, SP2);
    } else {
      k_pass2<1,0><<<NBLK2, 256, 0, stream>>>(SU, Q, nbr_fea, nullptr, nbr_idx,
                                              WEBf, SC1, SH1, SUMb, SP2);
    }
    k_redfin<<<64, 256, 0, stream>>>(SP2, 2*NBLK2, 128, 64, g2, bt2, SC2, SH2,
                                     1.f/(float)N);
    if(layer == 0)
      k_epi<<<2048, 256, 0, stream>>>(X, SUMb, SC2, SH2, A1);
  }

  // fused layer-1 epilogue + pool + head
  k_poolhead<<<N0, 128, 0, stream>>>(A1, SUMb, SC2, SH2, cid,
                                     W_fc, b_fc, W_out, b_out, out);
}